// Round 1
// baseline (1344.195 us; speedup 1.0000x reference)
//
#include <hip/hip_runtime.h>
#include <math.h>

#define N_TEAMS 100000
#define N_EDGES 1600000
#define BATCH   16384
#define DIM     64
#define SLOPE   0.01f

__device__ __forceinline__ float leaky(float v) { return v > 0.f ? v : SLOPE * v; }

// ---- degree / norm precompute -------------------------------------------

__global__ void k_deg_init(float* __restrict__ deg, int n) {
    int i = blockIdx.x * blockDim.x + threadIdx.x;
    if (i < n) deg[i] = 1.0f;  // self-loop weight
}

__global__ void k_deg_accum(const int* __restrict__ dst, const float* __restrict__ w,
                            float* __restrict__ deg, int E) {
    int e = blockIdx.x * blockDim.x + threadIdx.x;
    if (e < E) atomicAdd(&deg[dst[e]], w[e]);
}

__global__ void k_dinv(float* __restrict__ deg, int n) {
    int i = blockIdx.x * blockDim.x + threadIdx.x;
    if (i < n) {
        float d = deg[i];
        deg[i] = d > 0.f ? rsqrtf(fmaxf(d, 1e-12f)) : 0.f;
    }
}

__global__ void k_norm(const int* __restrict__ src, const int* __restrict__ dst,
                       const float* __restrict__ w, const float* __restrict__ dinv,
                       float* __restrict__ norm, int E) {
    int e = blockIdx.x * blockDim.x + threadIdx.x;
    if (e < E) norm[e] = dinv[src[e]] * w[e] * dinv[dst[e]];
}

// ---- per-layer: xw = x @ W ; acc = dinv^2 * xw + b (self-loop + bias) ----

__global__ __launch_bounds__(256) void k_gemm(
    const float* __restrict__ x, const float* __restrict__ W,
    const float* __restrict__ b, const float* __restrict__ dinv,
    float* __restrict__ xw, float* __restrict__ acc, int n) {
    __shared__ float Ws[64 * 64];
    __shared__ float xs[4 * 64];
    int tid = threadIdx.x;
#pragma unroll
    for (int i = 0; i < 16; i++) Ws[tid + i * 256] = W[tid + i * 256];
    int r = tid >> 6, c = tid & 63;
    int row = blockIdx.x * 4 + r;
    xs[tid] = (row < n) ? x[row * 64 + c] : 0.f;
    __syncthreads();
    if (row < n) {
        float s = 0.f;
#pragma unroll
        for (int k = 0; k < 64; k++) s = fmaf(xs[r * 64 + k], Ws[k * 64 + c], s);
        xw[row * 64 + c] = s;
        float di = dinv[row];
        acc[row * 64 + c] = fmaf(di * di, s, b[c]);
    }
}

// ---- edge scatter: acc[dst] += norm_e * xw[src] --------------------------

__global__ __launch_bounds__(256) void k_scatter(
    const int* __restrict__ src, const int* __restrict__ dst,
    const float* __restrict__ norm, const float* __restrict__ xw,
    float* __restrict__ acc, int E) {
    long long idx = (long long)blockIdx.x * blockDim.x + threadIdx.x;
    int e = (int)(idx >> 6);
    int d = (int)(idx & 63);
    if (e >= E) return;
    float nv = norm[e];
    float v = nv * xw[(long long)src[e] * 64 + d];
    atomicAdd(&acc[(long long)dst[e] * 64 + d], v);
}

// ---- leaky relu in-place (float4) ----------------------------------------

__global__ void k_leaky4(float* __restrict__ a, int n4) {
    int i = blockIdx.x * blockDim.x + threadIdx.x;
    if (i < n4) {
        float4 v = ((float4*)a)[i];
        v.x = leaky(v.x); v.y = leaky(v.y); v.z = leaky(v.z); v.w = leaky(v.w);
        ((float4*)a)[i] = v;
    }
}

// ---- head MLP: z2[B,3] ---------------------------------------------------

__global__ __launch_bounds__(256) void k_head(
    const float* __restrict__ x, const int* __restrict__ home,
    const int* __restrict__ away, const float* __restrict__ W1,
    const float* __restrict__ b1, const float* __restrict__ W3,
    const float* __restrict__ b3, float* __restrict__ z2, int B) {
    __shared__ float W1s[128 * 6];
    __shared__ float b1s[6], W3s[18], b3s[3];
    int tid = threadIdx.x;
    for (int i = tid; i < 768; i += 256) W1s[i] = W1[i];
    if (tid < 6) b1s[tid] = b1[tid];
    if (tid < 18) W3s[tid] = W3[tid];
    if (tid < 3) b3s[tid] = b3[tid];
    __syncthreads();
    int i = blockIdx.x * 256 + tid;
    if (i >= B) return;
    const float4* hr = (const float4*)(x + (long long)home[i] * 64);
    const float4* ar = (const float4*)(x + (long long)away[i] * 64);
    float h[128];
#pragma unroll
    for (int k = 0; k < 16; k++) {
        float4 v = hr[k];
        h[4 * k + 0] = v.x; h[4 * k + 1] = v.y; h[4 * k + 2] = v.z; h[4 * k + 3] = v.w;
    }
#pragma unroll
    for (int k = 0; k < 16; k++) {
        float4 v = ar[k];
        h[64 + 4 * k + 0] = v.x; h[64 + 4 * k + 1] = v.y; h[64 + 4 * k + 2] = v.z; h[64 + 4 * k + 3] = v.w;
    }
    float z1[6];
#pragma unroll
    for (int j = 0; j < 6; j++) z1[j] = b1s[j];
#pragma unroll 8
    for (int k = 0; k < 128; k++) {
        float hv = h[k];
#pragma unroll
        for (int j = 0; j < 6; j++) z1[j] = fmaf(hv, W1s[k * 6 + j], z1[j]);
    }
#pragma unroll
    for (int j = 0; j < 6; j++) z1[j] = leaky(z1[j]);
#pragma unroll
    for (int c = 0; c < 3; c++) {
        float s = b3s[c];
#pragma unroll
        for (int j = 0; j < 6; j++) s = fmaf(z1[j], W3s[j * 3 + c], s);
        z2[(long long)i * 3 + c] = leaky(s);
    }
}

// ---- column-wise log-softmax stats (single block) ------------------------

__global__ __launch_bounds__(1024) void k_stats(const float* __restrict__ z2,
                                                float* __restrict__ stats, int B) {
    __shared__ float red[3][1024];
    int tid = threadIdx.x;
    float m[3] = {-1e30f, -1e30f, -1e30f};
    for (int i = tid; i < B; i += 1024) {
        m[0] = fmaxf(m[0], z2[3 * i + 0]);
        m[1] = fmaxf(m[1], z2[3 * i + 1]);
        m[2] = fmaxf(m[2], z2[3 * i + 2]);
    }
    for (int c = 0; c < 3; c++) red[c][tid] = m[c];
    __syncthreads();
    for (int s = 512; s > 0; s >>= 1) {
        if (tid < s)
            for (int c = 0; c < 3; c++) red[c][tid] = fmaxf(red[c][tid], red[c][tid + s]);
        __syncthreads();
    }
    float M[3];
    for (int c = 0; c < 3; c++) M[c] = red[c][0];
    __syncthreads();
    float sum[3] = {0.f, 0.f, 0.f};
    for (int i = tid; i < B; i += 1024) {
        sum[0] += expf(z2[3 * i + 0] - M[0]);
        sum[1] += expf(z2[3 * i + 1] - M[1]);
        sum[2] += expf(z2[3 * i + 2] - M[2]);
    }
    for (int c = 0; c < 3; c++) red[c][tid] = sum[c];
    __syncthreads();
    for (int s = 512; s > 0; s >>= 1) {
        if (tid < s)
            for (int c = 0; c < 3; c++) red[c][tid] += red[c][tid + s];
        __syncthreads();
    }
    if (tid == 0) {
        for (int c = 0; c < 3; c++) {
            stats[c] = M[c];
            stats[3 + c] = logf(red[c][0]);
        }
    }
}

__global__ void k_final(const float* __restrict__ z2, const float* __restrict__ stats,
                        float* __restrict__ out, int n) {
    int i = blockIdx.x * blockDim.x + threadIdx.x;
    if (i < n) {
        int c = i % 3;
        out[i] = z2[i] - stats[c] - stats[3 + c];
    }
}

// ---- launch --------------------------------------------------------------

extern "C" void kernel_launch(void* const* d_in, const int* in_sizes, int n_in,
                              void* d_out, int out_size, void* d_ws, size_t ws_size,
                              hipStream_t stream) {
    const int*   edge_index = (const int*)d_in[0];
    const int*   src  = edge_index;
    const int*   dst  = edge_index + N_EDGES;
    const float* ew   = (const float*)d_in[1];
    const int*   home = (const int*)d_in[2];
    const int*   away = (const int*)d_in[3];
    const float* emb  = (const float*)d_in[4];
    const float* W0 = (const float*)d_in[5];  const float* b0 = (const float*)d_in[6];
    const float* W1 = (const float*)d_in[7];  const float* b1 = (const float*)d_in[8];
    const float* W2 = (const float*)d_in[9];  const float* b2 = (const float*)d_in[10];
    const float* l1W = (const float*)d_in[11]; const float* l1b = (const float*)d_in[12];
    const float* l3W = (const float*)d_in[13]; const float* l3b = (const float*)d_in[14];

    float* ws   = (float*)d_ws;
    float* dinv = ws;                          // N (padded to 100096)
    float* norm = dinv + 100096;               // E
    float* xw   = norm + N_EDGES;              // N*64
    float* bufA = xw + (size_t)N_TEAMS * 64;   // N*64
    float* bufB = bufA + (size_t)N_TEAMS * 64; // N*64
    float* z2   = bufB + (size_t)N_TEAMS * 64; // B*3
    float* stats = z2 + (size_t)BATCH * 3;     // 8

    // degrees + per-edge norms (shared by all 3 layers)
    k_deg_init<<<(N_TEAMS + 255) / 256, 256, 0, stream>>>(dinv, N_TEAMS);
    k_deg_accum<<<(N_EDGES + 255) / 256, 256, 0, stream>>>(dst, ew, dinv, N_EDGES);
    k_dinv<<<(N_TEAMS + 255) / 256, 256, 0, stream>>>(dinv, N_TEAMS);
    k_norm<<<(N_EDGES + 255) / 256, 256, 0, stream>>>(src, dst, ew, dinv, norm, N_EDGES);

    const int gemm_grid = (N_TEAMS + 3) / 4;
    const long long scat_threads = (long long)N_EDGES * 64;
    const int scat_grid = (int)((scat_threads + 255) / 256);
    const int relu_grid = (N_TEAMS * 64 / 4 + 255) / 256;

    // layer 0: emb -> bufA
    k_gemm<<<gemm_grid, 256, 0, stream>>>(emb, W0, b0, dinv, xw, bufA, N_TEAMS);
    k_scatter<<<scat_grid, 256, 0, stream>>>(src, dst, norm, xw, bufA, N_EDGES);
    k_leaky4<<<relu_grid, 256, 0, stream>>>(bufA, N_TEAMS * 64 / 4);
    // layer 1: bufA -> bufB
    k_gemm<<<gemm_grid, 256, 0, stream>>>(bufA, W1, b1, dinv, xw, bufB, N_TEAMS);
    k_scatter<<<scat_grid, 256, 0, stream>>>(src, dst, norm, xw, bufB, N_EDGES);
    k_leaky4<<<relu_grid, 256, 0, stream>>>(bufB, N_TEAMS * 64 / 4);
    // layer 2: bufB -> bufA
    k_gemm<<<gemm_grid, 256, 0, stream>>>(bufB, W2, b2, dinv, xw, bufA, N_TEAMS);
    k_scatter<<<scat_grid, 256, 0, stream>>>(src, dst, norm, xw, bufA, N_EDGES);
    k_leaky4<<<relu_grid, 256, 0, stream>>>(bufA, N_TEAMS * 64 / 4);

    // head + column log-softmax
    k_head<<<(BATCH + 255) / 256, 256, 0, stream>>>(bufA, home, away, l1W, l1b, l3W, l3b, z2, BATCH);
    k_stats<<<1, 1024, 0, stream>>>(z2, stats, BATCH);
    k_final<<<(BATCH * 3 + 255) / 256, 256, 0, stream>>>(z2, stats, (float*)d_out, BATCH * 3);
}

// Round 2
// 951.897 us; speedup vs baseline: 1.4121x; 1.4121x over previous
//
#include <hip/hip_runtime.h>
#include <math.h>

#define N_TEAMS 100000
#define N_EDGES 1600000
#define BATCH   16384
#define DIM     64
#define SLOPE   0.01f

__device__ __forceinline__ float leaky(float v) { return v > 0.f ? v : SLOPE * v; }

// ---- init: deg=1 (self-loop), cnt=0, fill=0 ------------------------------

__global__ void k_init(float* __restrict__ deg, int* __restrict__ cnt,
                       int* __restrict__ fill, int n) {
    int i = blockIdx.x * blockDim.x + threadIdx.x;
    if (i < n) { deg[i] = 1.0f; cnt[i] = 0; fill[i] = 0; }
}

// ---- histogram: in-degree count + weighted degree ------------------------

__global__ void k_hist(const int* __restrict__ dst, const float* __restrict__ w,
                       float* __restrict__ deg, int* __restrict__ cnt, int E) {
    int e = blockIdx.x * blockDim.x + threadIdx.x;
    if (e < E) {
        int d = dst[e];
        atomicAdd(&cnt[d], 1);
        atomicAdd(&deg[d], w[e]);
    }
}

__global__ void k_dinv(float* __restrict__ deg, int n) {
    int i = blockIdx.x * blockDim.x + threadIdx.x;
    if (i < n) {
        float d = deg[i];
        deg[i] = d > 0.f ? rsqrtf(fmaxf(d, 1e-12f)) : 0.f;
    }
}

// ---- 2-level exclusive scan of cnt -> row_start --------------------------

__global__ __launch_bounds__(1024) void k_scan1(const int* __restrict__ cnt,
                                                int* __restrict__ excl,
                                                int* __restrict__ partial, int n) {
    __shared__ int s[1024];
    int tid = threadIdx.x;
    int i = blockIdx.x * 1024 + tid;
    int v = (i < n) ? cnt[i] : 0;
    s[tid] = v;
    __syncthreads();
    for (int off = 1; off < 1024; off <<= 1) {
        int t = (tid >= off) ? s[tid - off] : 0;
        __syncthreads();
        s[tid] += t;
        __syncthreads();
    }
    excl[i] = s[tid] - v;
    if (tid == 1023) partial[blockIdx.x] = s[1023];
}

__global__ __launch_bounds__(128) void k_scan2(int* __restrict__ partial, int nb) {
    __shared__ int s[128];
    int tid = threadIdx.x;
    int v = (tid < nb) ? partial[tid] : 0;
    s[tid] = v;
    __syncthreads();
    for (int off = 1; off < 128; off <<= 1) {
        int t = (tid >= off) ? s[tid - off] : 0;
        __syncthreads();
        s[tid] += t;
        __syncthreads();
    }
    if (tid < nb) partial[tid] = s[tid] - v;  // exclusive
}

__global__ __launch_bounds__(1024) void k_scan3(int* __restrict__ row_start,
                                                const int* __restrict__ partial) {
    int i = blockIdx.x * 1024 + threadIdx.x;
    row_start[i] += partial[blockIdx.x];
}

// ---- bucket edges into CSR: packed (src, norm) ---------------------------

__global__ void k_bucket(const int* __restrict__ src, const int* __restrict__ dst,
                         const float* __restrict__ w, const float* __restrict__ dinv,
                         const int* __restrict__ row_start, int* __restrict__ fill,
                         int2* __restrict__ edges, int E) {
    int e = blockIdx.x * blockDim.x + threadIdx.x;
    if (e < E) {
        int s = src[e], d = dst[e];
        float nv = dinv[s] * w[e] * dinv[d];
        int p = row_start[d] + atomicAdd(&fill[d], 1);
        edges[p] = make_int2(s, __float_as_int(nv));
    }
}

// ---- aggregate: one wave per dst row; agg = dinv^2*x[r] + sum nv*x[src] --

__global__ __launch_bounds__(256) void k_agg(
    const float* __restrict__ x, const int* __restrict__ row_start,
    const int* __restrict__ cnt, const int2* __restrict__ edges,
    const float* __restrict__ dinv, float* __restrict__ out, int n) {
    int wid = (blockIdx.x * 256 + threadIdx.x) >> 6;
    int lane = threadIdx.x & 63;
    if (wid >= n) return;
    int beg = row_start[wid];
    int c = cnt[wid];
    float di = dinv[wid];
    float acc = di * di * x[(size_t)wid * 64 + lane];
    for (int j = 0; j < c; j++) {
        int2 ev = edges[beg + j];
        acc = fmaf(__int_as_float(ev.y), x[(size_t)ev.x * 64 + lane], acc);
    }
    out[(size_t)wid * 64 + lane] = acc;
}

// ---- gemm: out = leaky(in @ W + b), 16 rows/block ------------------------

__global__ __launch_bounds__(256) void k_gemm(
    const float* __restrict__ in, const float* __restrict__ W,
    const float* __restrict__ b, float* __restrict__ out, int n) {
    __shared__ float Ws[64 * 64];
    __shared__ float xs[16 * 64];
    int tid = threadIdx.x;
#pragma unroll
    for (int i = 0; i < 16; i++) Ws[tid + i * 256] = W[tid + i * 256];
    int row0 = blockIdx.x * 16;
#pragma unroll
    for (int j = 0; j < 4; j++) {
        int idx = tid + j * 256;
        int r = row0 + (idx >> 6);
        xs[idx] = (r < n) ? in[(size_t)r * 64 + (idx & 63)] : 0.f;
    }
    __syncthreads();
    int c = tid & 63, rr = tid >> 6;
    float acc[4] = {0.f, 0.f, 0.f, 0.f};
#pragma unroll
    for (int k = 0; k < 64; k++) {
        float wv = Ws[k * 64 + c];
#pragma unroll
        for (int i = 0; i < 4; i++) acc[i] = fmaf(xs[(4 * i + rr) * 64 + k], wv, acc[i]);
    }
    float bc = b[c];
#pragma unroll
    for (int i = 0; i < 4; i++) {
        int r = row0 + 4 * i + rr;
        if (r < n) out[(size_t)r * 64 + c] = leaky(acc[i] + bc);
    }
}

// ---- head MLP ------------------------------------------------------------

__global__ __launch_bounds__(256) void k_head(
    const float* __restrict__ x, const int* __restrict__ home,
    const int* __restrict__ away, const float* __restrict__ W1,
    const float* __restrict__ b1, const float* __restrict__ W3,
    const float* __restrict__ b3, float* __restrict__ z2, int B) {
    __shared__ float W1s[128 * 6];
    __shared__ float b1s[6], W3s[18], b3s[3];
    int tid = threadIdx.x;
    for (int i = tid; i < 768; i += 256) W1s[i] = W1[i];
    if (tid < 6) b1s[tid] = b1[tid];
    if (tid < 18) W3s[tid] = W3[tid];
    if (tid < 3) b3s[tid] = b3[tid];
    __syncthreads();
    int i = blockIdx.x * 256 + tid;
    if (i >= B) return;
    const float4* hr = (const float4*)(x + (size_t)home[i] * 64);
    const float4* ar = (const float4*)(x + (size_t)away[i] * 64);
    float z1[6];
#pragma unroll
    for (int j = 0; j < 6; j++) z1[j] = b1s[j];
#pragma unroll
    for (int k = 0; k < 16; k++) {
        float4 v = hr[k];
#pragma unroll
        for (int j = 0; j < 6; j++) {
            z1[j] = fmaf(v.x, W1s[(4 * k + 0) * 6 + j], z1[j]);
            z1[j] = fmaf(v.y, W1s[(4 * k + 1) * 6 + j], z1[j]);
            z1[j] = fmaf(v.z, W1s[(4 * k + 2) * 6 + j], z1[j]);
            z1[j] = fmaf(v.w, W1s[(4 * k + 3) * 6 + j], z1[j]);
        }
    }
#pragma unroll
    for (int k = 0; k < 16; k++) {
        float4 v = ar[k];
#pragma unroll
        for (int j = 0; j < 6; j++) {
            z1[j] = fmaf(v.x, W1s[(64 + 4 * k + 0) * 6 + j], z1[j]);
            z1[j] = fmaf(v.y, W1s[(64 + 4 * k + 1) * 6 + j], z1[j]);
            z1[j] = fmaf(v.z, W1s[(64 + 4 * k + 2) * 6 + j], z1[j]);
            z1[j] = fmaf(v.w, W1s[(64 + 4 * k + 3) * 6 + j], z1[j]);
        }
    }
#pragma unroll
    for (int j = 0; j < 6; j++) z1[j] = leaky(z1[j]);
#pragma unroll
    for (int c = 0; c < 3; c++) {
        float s = b3s[c];
#pragma unroll
        for (int j = 0; j < 6; j++) s = fmaf(z1[j], W3s[j * 3 + c], s);
        z2[(size_t)i * 3 + c] = leaky(s);
    }
}

// ---- column-wise log-softmax ---------------------------------------------

__global__ __launch_bounds__(1024) void k_stats(const float* __restrict__ z2,
                                                float* __restrict__ stats, int B) {
    __shared__ float red[3][1024];
    int tid = threadIdx.x;
    float m[3] = {-1e30f, -1e30f, -1e30f};
    for (int i = tid; i < B; i += 1024) {
        m[0] = fmaxf(m[0], z2[3 * i + 0]);
        m[1] = fmaxf(m[1], z2[3 * i + 1]);
        m[2] = fmaxf(m[2], z2[3 * i + 2]);
    }
    for (int c = 0; c < 3; c++) red[c][tid] = m[c];
    __syncthreads();
    for (int s = 512; s > 0; s >>= 1) {
        if (tid < s)
            for (int c = 0; c < 3; c++) red[c][tid] = fmaxf(red[c][tid], red[c][tid + s]);
        __syncthreads();
    }
    float M[3];
    for (int c = 0; c < 3; c++) M[c] = red[c][0];
    __syncthreads();
    float sum[3] = {0.f, 0.f, 0.f};
    for (int i = tid; i < B; i += 1024) {
        sum[0] += expf(z2[3 * i + 0] - M[0]);
        sum[1] += expf(z2[3 * i + 1] - M[1]);
        sum[2] += expf(z2[3 * i + 2] - M[2]);
    }
    for (int c = 0; c < 3; c++) red[c][tid] = sum[c];
    __syncthreads();
    for (int s = 512; s > 0; s >>= 1) {
        if (tid < s)
            for (int c = 0; c < 3; c++) red[c][tid] += red[c][tid + s];
        __syncthreads();
    }
    if (tid == 0)
        for (int c = 0; c < 3; c++) { stats[c] = M[c]; stats[3 + c] = logf(red[c][0]); }
}

__global__ void k_final(const float* __restrict__ z2, const float* __restrict__ stats,
                        float* __restrict__ out, int n) {
    int i = blockIdx.x * blockDim.x + threadIdx.x;
    if (i < n) {
        int c = i % 3;
        out[i] = z2[i] - stats[c] - stats[3 + c];
    }
}

// ---- launch --------------------------------------------------------------

extern "C" void kernel_launch(void* const* d_in, const int* in_sizes, int n_in,
                              void* d_out, int out_size, void* d_ws, size_t ws_size,
                              hipStream_t stream) {
    const int*   edge_index = (const int*)d_in[0];
    const int*   src  = edge_index;
    const int*   dst  = edge_index + N_EDGES;
    const float* ew   = (const float*)d_in[1];
    const int*   home = (const int*)d_in[2];
    const int*   away = (const int*)d_in[3];
    const float* emb  = (const float*)d_in[4];
    const float* W0 = (const float*)d_in[5];  const float* b0 = (const float*)d_in[6];
    const float* W1 = (const float*)d_in[7];  const float* b1 = (const float*)d_in[8];
    const float* W2 = (const float*)d_in[9];  const float* b2 = (const float*)d_in[10];
    const float* l1W = (const float*)d_in[11]; const float* l1b = (const float*)d_in[12];
    const float* l3W = (const float*)d_in[13]; const float* l3b = (const float*)d_in[14];

    const int NPAD = 100352;  // 98 * 1024
    char* p = (char*)d_ws;
    float* dinv      = (float*)p;            p += NPAD * 4;
    int*   cnt       = (int*)p;              p += NPAD * 4;
    int*   fill      = (int*)p;              p += NPAD * 4;
    int*   row_start = (int*)p;              p += NPAD * 4;
    int*   partial   = (int*)p;              p += 128 * 4;
    int2*  edges     = (int2*)p;             p += (size_t)N_EDGES * 8;
    float* aggbuf    = (float*)p;            p += (size_t)N_TEAMS * 64 * 4;
    float* bufA      = (float*)p;            p += (size_t)N_TEAMS * 64 * 4;
    float* z2        = (float*)p;            p += (size_t)BATCH * 3 * 4;
    float* stats     = (float*)p;

    const int scanBlocks = NPAD / 1024;  // 98

    // ---- CSR build (once, reused by all 3 layers) ----
    k_init<<<(N_TEAMS + 255) / 256, 256, 0, stream>>>(dinv, cnt, fill, N_TEAMS);
    k_hist<<<(N_EDGES + 255) / 256, 256, 0, stream>>>(dst, ew, dinv, cnt, N_EDGES);
    k_dinv<<<(N_TEAMS + 255) / 256, 256, 0, stream>>>(dinv, N_TEAMS);
    k_scan1<<<scanBlocks, 1024, 0, stream>>>(cnt, row_start, partial, N_TEAMS);
    k_scan2<<<1, 128, 0, stream>>>(partial, scanBlocks);
    k_scan3<<<scanBlocks, 1024, 0, stream>>>(row_start, partial);
    k_bucket<<<(N_EDGES + 255) / 256, 256, 0, stream>>>(src, dst, ew, dinv, row_start,
                                                        fill, edges, N_EDGES);

    const int agg_grid  = (N_TEAMS * 64 + 255) / 256;
    const int gemm_grid = (N_TEAMS + 15) / 16;

    // layer 0: emb -> aggbuf -> bufA
    k_agg<<<agg_grid, 256, 0, stream>>>(emb, row_start, cnt, edges, dinv, aggbuf, N_TEAMS);
    k_gemm<<<gemm_grid, 256, 0, stream>>>(aggbuf, W0, b0, bufA, N_TEAMS);
    // layer 1: bufA -> aggbuf -> bufA
    k_agg<<<agg_grid, 256, 0, stream>>>(bufA, row_start, cnt, edges, dinv, aggbuf, N_TEAMS);
    k_gemm<<<gemm_grid, 256, 0, stream>>>(aggbuf, W1, b1, bufA, N_TEAMS);
    // layer 2: bufA -> aggbuf -> bufA
    k_agg<<<agg_grid, 256, 0, stream>>>(bufA, row_start, cnt, edges, dinv, aggbuf, N_TEAMS);
    k_gemm<<<gemm_grid, 256, 0, stream>>>(aggbuf, W2, b2, bufA, N_TEAMS);

    // head + column log-softmax
    k_head<<<(BATCH + 255) / 256, 256, 0, stream>>>(bufA, home, away, l1W, l1b, l3W, l3b, z2, BATCH);
    k_stats<<<1, 1024, 0, stream>>>(z2, stats, BATCH);
    k_final<<<(BATCH * 3 + 255) / 256, 256, 0, stream>>>(z2, stats, (float*)d_out, BATCH * 3);
}

// Round 3
// 803.129 us; speedup vs baseline: 1.6737x; 1.1852x over previous
//
#include <hip/hip_runtime.h>
#include <math.h>

#define N_TEAMS 100000
#define N_EDGES 1600000
#define BATCH   16384
#define DIM     64
#define SLOPE   0.01f

__device__ __forceinline__ float leaky(float v) { return v > 0.f ? v : SLOPE * v; }

__device__ __forceinline__ float bf2f(unsigned short u) {
    return __uint_as_float(((unsigned)u) << 16);
}
__device__ __forceinline__ unsigned short f2bf(float f) {
    unsigned b = __float_as_uint(f);
    unsigned r = b + 0x7FFFu + ((b >> 16) & 1u);  // RNE
    return (unsigned short)(r >> 16);
}
__device__ __forceinline__ float2 bf2x2(unsigned u) {
    float2 r;
    r.x = __uint_as_float(u << 16);
    r.y = __uint_as_float(u & 0xFFFF0000u);
    return r;
}

// ---- init: deg=1 (self-loop), cnt=0, fill=0 ------------------------------

__global__ void k_init(float* __restrict__ deg, int* __restrict__ cnt,
                       int* __restrict__ fill, int n) {
    int i = blockIdx.x * blockDim.x + threadIdx.x;
    if (i < n) { deg[i] = 1.0f; cnt[i] = 0; fill[i] = 0; }
}

__global__ void k_hist(const int* __restrict__ dst, const float* __restrict__ w,
                       float* __restrict__ deg, int* __restrict__ cnt, int E) {
    int e = blockIdx.x * blockDim.x + threadIdx.x;
    if (e < E) {
        int d = dst[e];
        atomicAdd(&cnt[d], 1);
        atomicAdd(&deg[d], w[e]);
    }
}

__global__ void k_dinv(float* __restrict__ deg, int n) {
    int i = blockIdx.x * blockDim.x + threadIdx.x;
    if (i < n) {
        float d = deg[i];
        deg[i] = d > 0.f ? rsqrtf(fmaxf(d, 1e-12f)) : 0.f;
    }
}

// ---- 2-level exclusive scan of cnt -> row_start --------------------------

__global__ __launch_bounds__(1024) void k_scan1(const int* __restrict__ cnt,
                                                int* __restrict__ excl,
                                                int* __restrict__ partial, int n) {
    __shared__ int s[1024];
    int tid = threadIdx.x;
    int i = blockIdx.x * 1024 + tid;
    int v = (i < n) ? cnt[i] : 0;
    s[tid] = v;
    __syncthreads();
    for (int off = 1; off < 1024; off <<= 1) {
        int t = (tid >= off) ? s[tid - off] : 0;
        __syncthreads();
        s[tid] += t;
        __syncthreads();
    }
    excl[i] = s[tid] - v;
    if (tid == 1023) partial[blockIdx.x] = s[1023];
}

__global__ __launch_bounds__(128) void k_scan2(int* __restrict__ partial, int nb) {
    __shared__ int s[128];
    int tid = threadIdx.x;
    int v = (tid < nb) ? partial[tid] : 0;
    s[tid] = v;
    __syncthreads();
    for (int off = 1; off < 128; off <<= 1) {
        int t = (tid >= off) ? s[tid - off] : 0;
        __syncthreads();
        s[tid] += t;
        __syncthreads();
    }
    if (tid < nb) partial[tid] = s[tid] - v;  // exclusive
}

__global__ __launch_bounds__(1024) void k_scan3(int* __restrict__ row_start,
                                                const int* __restrict__ partial) {
    int i = blockIdx.x * 1024 + threadIdx.x;
    row_start[i] += partial[blockIdx.x];
}

// ---- bucket edges into CSR: packed (src, norm) ---------------------------

__global__ void k_bucket(const int* __restrict__ src, const int* __restrict__ dst,
                         const float* __restrict__ w, const float* __restrict__ dinv,
                         const int* __restrict__ row_start, int* __restrict__ fill,
                         int2* __restrict__ edges, int E) {
    int e = blockIdx.x * blockDim.x + threadIdx.x;
    if (e < E) {
        int s = src[e], d = dst[e];
        float nv = dinv[s] * w[e] * dinv[d];
        int p = row_start[d] + atomicAdd(&fill[d], 1);
        edges[p] = make_int2(s, __float_as_int(nv));
    }
}

// ---- emb f32 -> bf16 table -----------------------------------------------

__global__ void k_cvt(const float* __restrict__ x, unsigned short* __restrict__ xb,
                      int n4) {
    int i = blockIdx.x * blockDim.x + threadIdx.x;
    if (i < n4) {
        float4 v = ((const float4*)x)[i];
        ushort4 o;
        o.x = f2bf(v.x); o.y = f2bf(v.y); o.z = f2bf(v.z); o.w = f2bf(v.w);
        ((ushort4*)xb)[i] = o;
    }
}

// ---- fused layer: y = leaky((A @ x) @ W + b), one wave per dst row -------
// lane = feature dim; gather bf16 rows, accumulate f32, in-wave GEMM via
// readlane broadcast against W staged in LDS, write bf16.

__global__ __launch_bounds__(256) void k_layer(
    const unsigned short* __restrict__ xb, const int* __restrict__ row_start,
    const int* __restrict__ cnt, const int2* __restrict__ edges,
    const float* __restrict__ dinv, const float* __restrict__ W,
    const float* __restrict__ b, unsigned short* __restrict__ yb, int n) {
    __shared__ float Ws[64 * 64];
    int tid = threadIdx.x;
#pragma unroll
    for (int i = 0; i < 16; i++) Ws[tid + i * 256] = W[tid + i * 256];
    __syncthreads();
    int wid = (blockIdx.x * 256 + tid) >> 6;
    int lane = tid & 63;
    if (wid >= n) return;
    int beg = row_start[wid];
    int c = cnt[wid];
    float di = dinv[wid];
    float acc = di * di * bf2f(xb[(size_t)wid * 64 + lane]);
    for (int j = 0; j < c; j++) {
        int2 ev = edges[beg + j];
        acc = fmaf(__int_as_float(ev.y), bf2f(xb[(size_t)ev.x * 64 + lane]), acc);
    }
    // in-wave GEMM: o[lane] = sum_k acc[k] * W[k][lane]
    float o = b[lane];
#pragma unroll
    for (int k = 0; k < 64; k++) {
        float xk = __shfl(acc, k, 64);
        o = fmaf(xk, Ws[k * 64 + lane], o);
    }
    yb[(size_t)wid * 64 + lane] = f2bf(leaky(o));
}

// ---- head MLP (bf16 activations in) --------------------------------------

__global__ __launch_bounds__(256) void k_head(
    const unsigned short* __restrict__ xb, const int* __restrict__ home,
    const int* __restrict__ away, const float* __restrict__ W1,
    const float* __restrict__ b1, const float* __restrict__ W3,
    const float* __restrict__ b3, float* __restrict__ z2, int B) {
    __shared__ float W1s[128 * 6];
    __shared__ float b1s[6], W3s[18], b3s[3];
    int tid = threadIdx.x;
    for (int i = tid; i < 768; i += 256) W1s[i] = W1[i];
    if (tid < 6) b1s[tid] = b1[tid];
    if (tid < 18) W3s[tid] = W3[tid];
    if (tid < 3) b3s[tid] = b3[tid];
    __syncthreads();
    int i = blockIdx.x * 256 + tid;
    if (i >= B) return;
    float z1[6];
#pragma unroll
    for (int j = 0; j < 6; j++) z1[j] = b1s[j];
    const uint4* rows[2];
    rows[0] = (const uint4*)(xb + (size_t)home[i] * 64);
    rows[1] = (const uint4*)(xb + (size_t)away[i] * 64);
#pragma unroll
    for (int h = 0; h < 2; h++) {
        const uint4* r = rows[h];
        int base = h * 64;
#pragma unroll
        for (int k = 0; k < 8; k++) {   // 8 x uint4 = 8 x 8 bf16 = 64 dims
            uint4 v = r[k];
            unsigned uu[4] = {v.x, v.y, v.z, v.w};
#pragma unroll
            for (int t = 0; t < 4; t++) {
                float2 f = bf2x2(uu[t]);
                int d = base + k * 8 + t * 2;
#pragma unroll
                for (int j = 0; j < 6; j++) {
                    z1[j] = fmaf(f.x, W1s[d * 6 + j], z1[j]);
                    z1[j] = fmaf(f.y, W1s[(d + 1) * 6 + j], z1[j]);
                }
            }
        }
    }
#pragma unroll
    for (int j = 0; j < 6; j++) z1[j] = leaky(z1[j]);
#pragma unroll
    for (int c = 0; c < 3; c++) {
        float s = b3s[c];
#pragma unroll
        for (int j = 0; j < 6; j++) s = fmaf(z1[j], W3s[j * 3 + c], s);
        z2[(size_t)i * 3 + c] = leaky(s);
    }
}

// ---- column-wise log-softmax ---------------------------------------------

__global__ __launch_bounds__(1024) void k_stats(const float* __restrict__ z2,
                                                float* __restrict__ stats, int B) {
    __shared__ float red[3][1024];
    int tid = threadIdx.x;
    float m[3] = {-1e30f, -1e30f, -1e30f};
    for (int i = tid; i < B; i += 1024) {
        m[0] = fmaxf(m[0], z2[3 * i + 0]);
        m[1] = fmaxf(m[1], z2[3 * i + 1]);
        m[2] = fmaxf(m[2], z2[3 * i + 2]);
    }
    for (int c = 0; c < 3; c++) red[c][tid] = m[c];
    __syncthreads();
    for (int s = 512; s > 0; s >>= 1) {
        if (tid < s)
            for (int c = 0; c < 3; c++) red[c][tid] = fmaxf(red[c][tid], red[c][tid + s]);
        __syncthreads();
    }
    float M[3];
    for (int c = 0; c < 3; c++) M[c] = red[c][0];
    __syncthreads();
    float sum[3] = {0.f, 0.f, 0.f};
    for (int i = tid; i < B; i += 1024) {
        sum[0] += expf(z2[3 * i + 0] - M[0]);
        sum[1] += expf(z2[3 * i + 1] - M[1]);
        sum[2] += expf(z2[3 * i + 2] - M[2]);
    }
    for (int c = 0; c < 3; c++) red[c][tid] = sum[c];
    __syncthreads();
    for (int s = 512; s > 0; s >>= 1) {
        if (tid < s)
            for (int c = 0; c < 3; c++) red[c][tid] += red[c][tid + s];
        __syncthreads();
    }
    if (tid == 0)
        for (int c = 0; c < 3; c++) { stats[c] = M[c]; stats[3 + c] = logf(red[c][0]); }
}

__global__ void k_final(const float* __restrict__ z2, const float* __restrict__ stats,
                        float* __restrict__ out, int n) {
    int i = blockIdx.x * blockDim.x + threadIdx.x;
    if (i < n) {
        int c = i % 3;
        out[i] = z2[i] - stats[c] - stats[3 + c];
    }
}

// ---- launch --------------------------------------------------------------

extern "C" void kernel_launch(void* const* d_in, const int* in_sizes, int n_in,
                              void* d_out, int out_size, void* d_ws, size_t ws_size,
                              hipStream_t stream) {
    const int*   edge_index = (const int*)d_in[0];
    const int*   src  = edge_index;
    const int*   dst  = edge_index + N_EDGES;
    const float* ew   = (const float*)d_in[1];
    const int*   home = (const int*)d_in[2];
    const int*   away = (const int*)d_in[3];
    const float* emb  = (const float*)d_in[4];
    const float* W0 = (const float*)d_in[5];  const float* b0 = (const float*)d_in[6];
    const float* W1 = (const float*)d_in[7];  const float* b1 = (const float*)d_in[8];
    const float* W2 = (const float*)d_in[9];  const float* b2 = (const float*)d_in[10];
    const float* l1W = (const float*)d_in[11]; const float* l1b = (const float*)d_in[12];
    const float* l3W = (const float*)d_in[13]; const float* l3b = (const float*)d_in[14];

    const int NPAD = 100352;  // 98 * 1024
    char* p = (char*)d_ws;
    float*          dinv      = (float*)p;          p += NPAD * 4;
    int*            cnt       = (int*)p;            p += NPAD * 4;
    int*            fill      = (int*)p;            p += NPAD * 4;
    int*            row_start = (int*)p;            p += NPAD * 4;
    int*            partial   = (int*)p;            p += 128 * 4;
    int2*           edges     = (int2*)p;           p += (size_t)N_EDGES * 8;
    unsigned short* xbA       = (unsigned short*)p; p += (size_t)N_TEAMS * 64 * 2;
    unsigned short* xbB       = (unsigned short*)p; p += (size_t)N_TEAMS * 64 * 2;
    float*          z2        = (float*)p;          p += (size_t)BATCH * 3 * 4;
    float*          stats     = (float*)p;

    const int scanBlocks = NPAD / 1024;  // 98

    // ---- CSR build (once, reused by all 3 layers) ----
    k_init<<<(N_TEAMS + 255) / 256, 256, 0, stream>>>(dinv, cnt, fill, N_TEAMS);
    k_hist<<<(N_EDGES + 255) / 256, 256, 0, stream>>>(dst, ew, dinv, cnt, N_EDGES);
    k_dinv<<<(N_TEAMS + 255) / 256, 256, 0, stream>>>(dinv, N_TEAMS);
    k_scan1<<<scanBlocks, 1024, 0, stream>>>(cnt, row_start, partial, N_TEAMS);
    k_scan2<<<1, 128, 0, stream>>>(partial, scanBlocks);
    k_scan3<<<scanBlocks, 1024, 0, stream>>>(row_start, partial);
    k_bucket<<<(N_EDGES + 255) / 256, 256, 0, stream>>>(src, dst, ew, dinv, row_start,
                                                        fill, edges, N_EDGES);
    k_cvt<<<(N_TEAMS * 64 / 4 + 255) / 256, 256, 0, stream>>>(emb, xbA, N_TEAMS * 64 / 4);

    const int layer_grid = N_TEAMS * 64 / 256;  // 25000, exact

    // layer 0..2 fused: agg + GEMM + bias + leaky
    k_layer<<<layer_grid, 256, 0, stream>>>(xbA, row_start, cnt, edges, dinv, W0, b0, xbB, N_TEAMS);
    k_layer<<<layer_grid, 256, 0, stream>>>(xbB, row_start, cnt, edges, dinv, W1, b1, xbA, N_TEAMS);
    k_layer<<<layer_grid, 256, 0, stream>>>(xbA, row_start, cnt, edges, dinv, W2, b2, xbB, N_TEAMS);

    // head + column log-softmax
    k_head<<<(BATCH + 255) / 256, 256, 0, stream>>>(xbB, home, away, l1W, l1b, l3W, l3b, z2, BATCH);
    k_stats<<<1, 1024, 0, stream>>>(z2, stats, BATCH);
    k_final<<<(BATCH * 3 + 255) / 256, 256, 0, stream>>>(z2, stats, (float*)d_out, BATCH * 3);
}

// Round 4
// 660.027 us; speedup vs baseline: 2.0366x; 1.2168x over previous
//
#include <hip/hip_runtime.h>
#include <math.h>

#define N_TEAMS 100000
#define N_EDGES 1600000
#define BATCH   16384
#define DIM     64
#define SLOPE   0.01f

__device__ __forceinline__ float leaky(float v) { return v > 0.f ? v : SLOPE * v; }

__device__ __forceinline__ float bf2f(unsigned short u) {
    return __uint_as_float(((unsigned)u) << 16);
}
__device__ __forceinline__ unsigned short f2bf(float f) {
    unsigned b = __float_as_uint(f);
    unsigned r = b + 0x7FFFu + ((b >> 16) & 1u);  // RNE
    return (unsigned short)(r >> 16);
}
__device__ __forceinline__ float2 bf2x2(unsigned u) {
    float2 r;
    r.x = __uint_as_float(u << 16);
    r.y = __uint_as_float(u & 0xFFFF0000u);
    return r;
}

// ---- init: deg=1 (self-loop), cnt=0, fill=0 ------------------------------

__global__ void k_init(float* __restrict__ deg, int* __restrict__ cnt,
                       int* __restrict__ fill, int n) {
    int i = blockIdx.x * blockDim.x + threadIdx.x;
    if (i < n) { deg[i] = 1.0f; cnt[i] = 0; fill[i] = 0; }
}

__global__ void k_hist(const int* __restrict__ dst, const float* __restrict__ w,
                       float* __restrict__ deg, int* __restrict__ cnt, int E) {
    int e = blockIdx.x * blockDim.x + threadIdx.x;
    if (e < E) {
        int d = dst[e];
        atomicAdd(&cnt[d], 1);
        atomicAdd(&deg[d], w[e]);
    }
}

__global__ void k_dinv(float* __restrict__ deg, int n) {
    int i = blockIdx.x * blockDim.x + threadIdx.x;
    if (i < n) {
        float d = deg[i];
        deg[i] = d > 0.f ? rsqrtf(fmaxf(d, 1e-12f)) : 0.f;
    }
}

// ---- 2-level exclusive scan of cnt -> row_start --------------------------

__global__ __launch_bounds__(1024) void k_scan1(const int* __restrict__ cnt,
                                                int* __restrict__ excl,
                                                int* __restrict__ partial, int n) {
    __shared__ int s[1024];
    int tid = threadIdx.x;
    int i = blockIdx.x * 1024 + tid;
    int v = (i < n) ? cnt[i] : 0;
    s[tid] = v;
    __syncthreads();
    for (int off = 1; off < 1024; off <<= 1) {
        int t = (tid >= off) ? s[tid - off] : 0;
        __syncthreads();
        s[tid] += t;
        __syncthreads();
    }
    excl[i] = s[tid] - v;
    if (tid == 1023) partial[blockIdx.x] = s[1023];
}

__global__ __launch_bounds__(128) void k_scan2(int* __restrict__ partial, int nb) {
    __shared__ int s[128];
    int tid = threadIdx.x;
    int v = (tid < nb) ? partial[tid] : 0;
    s[tid] = v;
    __syncthreads();
    for (int off = 1; off < 128; off <<= 1) {
        int t = (tid >= off) ? s[tid - off] : 0;
        __syncthreads();
        s[tid] += t;
        __syncthreads();
    }
    if (tid < nb) partial[tid] = s[tid] - v;  // exclusive
}

__global__ __launch_bounds__(1024) void k_scan3(int* __restrict__ row_start,
                                                const int* __restrict__ partial) {
    int i = blockIdx.x * 1024 + threadIdx.x;
    row_start[i] += partial[blockIdx.x];
}

// ---- bucket edges into CSR: packed (src, norm) ---------------------------

__global__ void k_bucket(const int* __restrict__ src, const int* __restrict__ dst,
                         const float* __restrict__ w, const float* __restrict__ dinv,
                         const int* __restrict__ row_start, int* __restrict__ fill,
                         int2* __restrict__ edges, int E) {
    int e = blockIdx.x * blockDim.x + threadIdx.x;
    if (e < E) {
        int s = src[e], d = dst[e];
        float nv = dinv[s] * w[e] * dinv[d];
        int p = row_start[d] + atomicAdd(&fill[d], 1);
        edges[p] = make_int2(s, __float_as_int(nv));
    }
}

// ---- emb f32 -> bf16 table -----------------------------------------------

__global__ void k_cvt(const float* __restrict__ x, unsigned short* __restrict__ xb,
                      int n4) {
    int i = blockIdx.x * blockDim.x + threadIdx.x;
    if (i < n4) {
        float4 v = ((const float4*)x)[i];
        ushort4 o;
        o.x = f2bf(v.x); o.y = f2bf(v.y); o.z = f2bf(v.z); o.w = f2bf(v.w);
        ((ushort4*)xb)[i] = o;
    }
}

// ---- fused layer: y = leaky((A @ x) @ W + b), one wave per dst row -------
// 8-deep software-pipelined gather: nontemporal edge loads (stream-once,
// keep x-table in L2), 8 outstanding row-gathers per wave.

__global__ __launch_bounds__(256) void k_layer(
    const unsigned short* __restrict__ xb, const int* __restrict__ row_start,
    const int* __restrict__ cnt, const int2* __restrict__ edges,
    const float* __restrict__ dinv, const float* __restrict__ W,
    const float* __restrict__ b, unsigned short* __restrict__ yb, int n) {
    __shared__ float Ws[64 * 64];
    int tid = threadIdx.x;
#pragma unroll
    for (int i = 0; i < 16; i++) Ws[tid + i * 256] = W[tid + i * 256];
    __syncthreads();
    int wid = (blockIdx.x * 256 + tid) >> 6;
    int lane = tid & 63;
    if (wid >= n) return;
    int beg = row_start[wid];
    int c = cnt[wid];
    float di = dinv[wid];
    float acc = di * di * bf2f(xb[(size_t)wid * 64 + lane]);

    const long long* ep = (const long long*)(edges + beg);
    int j = 0;
    int chunks = c >> 3;
    if (chunks > 0) {
        long long ev[8];
#pragma unroll
        for (int k = 0; k < 8; k++) ev[k] = __builtin_nontemporal_load(ep + k);
        for (int t = 1; t <= chunks; t++) {
            float nv[8], xv[8];
#pragma unroll
            for (int k = 0; k < 8; k++) {
                int s = (int)ev[k];
                nv[k] = __int_as_float((int)(ev[k] >> 32));
                xv[k] = bf2f(xb[(size_t)s * 64 + lane]);  // 8 independent gathers
            }
            if (t < chunks) {
                const long long* np = ep + (size_t)t * 8;
#pragma unroll
                for (int k = 0; k < 8; k++) ev[k] = __builtin_nontemporal_load(np + k);
            }
#pragma unroll
            for (int k = 0; k < 8; k++) acc = fmaf(nv[k], xv[k], acc);
        }
        j = chunks * 8;
    }
    if (j + 4 <= c) {
        long long e0 = __builtin_nontemporal_load(ep + j + 0);
        long long e1 = __builtin_nontemporal_load(ep + j + 1);
        long long e2 = __builtin_nontemporal_load(ep + j + 2);
        long long e3 = __builtin_nontemporal_load(ep + j + 3);
        float x0 = bf2f(xb[(size_t)(int)e0 * 64 + lane]);
        float x1 = bf2f(xb[(size_t)(int)e1 * 64 + lane]);
        float x2 = bf2f(xb[(size_t)(int)e2 * 64 + lane]);
        float x3 = bf2f(xb[(size_t)(int)e3 * 64 + lane]);
        acc = fmaf(__int_as_float((int)(e0 >> 32)), x0, acc);
        acc = fmaf(__int_as_float((int)(e1 >> 32)), x1, acc);
        acc = fmaf(__int_as_float((int)(e2 >> 32)), x2, acc);
        acc = fmaf(__int_as_float((int)(e3 >> 32)), x3, acc);
        j += 4;
    }
    for (; j < c; j++) {
        long long e0 = __builtin_nontemporal_load(ep + j);
        acc = fmaf(__int_as_float((int)(e0 >> 32)),
                   bf2f(xb[(size_t)(int)e0 * 64 + lane]), acc);
    }

    // in-wave GEMM: o[lane] = sum_k acc[k] * W[k][lane]
    float o = b[lane];
#pragma unroll
    for (int k = 0; k < 64; k++) {
        float xk = __shfl(acc, k, 64);
        o = fmaf(xk, Ws[k * 64 + lane], o);
    }
    yb[(size_t)wid * 64 + lane] = f2bf(leaky(o));
}

// ---- head MLP (bf16 activations in) --------------------------------------

__global__ __launch_bounds__(256) void k_head(
    const unsigned short* __restrict__ xb, const int* __restrict__ home,
    const int* __restrict__ away, const float* __restrict__ W1,
    const float* __restrict__ b1, const float* __restrict__ W3,
    const float* __restrict__ b3, float* __restrict__ z2, int B) {
    __shared__ float W1s[128 * 6];
    __shared__ float b1s[6], W3s[18], b3s[3];
    int tid = threadIdx.x;
    for (int i = tid; i < 768; i += 256) W1s[i] = W1[i];
    if (tid < 6) b1s[tid] = b1[tid];
    if (tid < 18) W3s[tid] = W3[tid];
    if (tid < 3) b3s[tid] = b3[tid];
    __syncthreads();
    int i = blockIdx.x * 256 + tid;
    if (i >= B) return;
    float z1[6];
#pragma unroll
    for (int j = 0; j < 6; j++) z1[j] = b1s[j];
    const uint4* rows[2];
    rows[0] = (const uint4*)(xb + (size_t)home[i] * 64);
    rows[1] = (const uint4*)(xb + (size_t)away[i] * 64);
#pragma unroll
    for (int h = 0; h < 2; h++) {
        const uint4* r = rows[h];
        int base = h * 64;
#pragma unroll
        for (int k = 0; k < 8; k++) {
            uint4 v = r[k];
            unsigned uu[4] = {v.x, v.y, v.z, v.w};
#pragma unroll
            for (int t = 0; t < 4; t++) {
                float2 f = bf2x2(uu[t]);
                int d = base + k * 8 + t * 2;
#pragma unroll
                for (int j = 0; j < 6; j++) {
                    z1[j] = fmaf(f.x, W1s[d * 6 + j], z1[j]);
                    z1[j] = fmaf(f.y, W1s[(d + 1) * 6 + j], z1[j]);
                }
            }
        }
    }
#pragma unroll
    for (int j = 0; j < 6; j++) z1[j] = leaky(z1[j]);
#pragma unroll
    for (int c = 0; c < 3; c++) {
        float s = b3s[c];
#pragma unroll
        for (int j = 0; j < 6; j++) s = fmaf(z1[j], W3s[j * 3 + c], s);
        z2[(size_t)i * 3 + c] = leaky(s);
    }
}

// ---- column-wise log-softmax ---------------------------------------------

__global__ __launch_bounds__(1024) void k_stats(const float* __restrict__ z2,
                                                float* __restrict__ stats, int B) {
    __shared__ float red[3][1024];
    int tid = threadIdx.x;
    float m[3] = {-1e30f, -1e30f, -1e30f};
    for (int i = tid; i < B; i += 1024) {
        m[0] = fmaxf(m[0], z2[3 * i + 0]);
        m[1] = fmaxf(m[1], z2[3 * i + 1]);
        m[2] = fmaxf(m[2], z2[3 * i + 2]);
    }
    for (int c = 0; c < 3; c++) red[c][tid] = m[c];
    __syncthreads();
    for (int s = 512; s > 0; s >>= 1) {
        if (tid < s)
            for (int c = 0; c < 3; c++) red[c][tid] = fmaxf(red[c][tid], red[c][tid + s]);
        __syncthreads();
    }
    float M[3];
    for (int c = 0; c < 3; c++) M[c] = red[c][0];
    __syncthreads();
    float sum[3] = {0.f, 0.f, 0.f};
    for (int i = tid; i < B; i += 1024) {
        sum[0] += expf(z2[3 * i + 0] - M[0]);
        sum[1] += expf(z2[3 * i + 1] - M[1]);
        sum[2] += expf(z2[3 * i + 2] - M[2]);
    }
    for (int c = 0; c < 3; c++) red[c][tid] = sum[c];
    __syncthreads();
    for (int s = 512; s > 0; s >>= 1) {
        if (tid < s)
            for (int c = 0; c < 3; c++) red[c][tid] += red[c][tid + s];
        __syncthreads();
    }
    if (tid == 0)
        for (int c = 0; c < 3; c++) { stats[c] = M[c]; stats[3 + c] = logf(red[c][0]); }
}

__global__ void k_final(const float* __restrict__ z2, const float* __restrict__ stats,
                        float* __restrict__ out, int n) {
    int i = blockIdx.x * blockDim.x + threadIdx.x;
    if (i < n) {
        int c = i % 3;
        out[i] = z2[i] - stats[c] - stats[3 + c];
    }
}

// ---- launch --------------------------------------------------------------

extern "C" void kernel_launch(void* const* d_in, const int* in_sizes, int n_in,
                              void* d_out, int out_size, void* d_ws, size_t ws_size,
                              hipStream_t stream) {
    const int*   edge_index = (const int*)d_in[0];
    const int*   src  = edge_index;
    const int*   dst  = edge_index + N_EDGES;
    const float* ew   = (const float*)d_in[1];
    const int*   home = (const int*)d_in[2];
    const int*   away = (const int*)d_in[3];
    const float* emb  = (const float*)d_in[4];
    const float* W0 = (const float*)d_in[5];  const float* b0 = (const float*)d_in[6];
    const float* W1 = (const float*)d_in[7];  const float* b1 = (const float*)d_in[8];
    const float* W2 = (const float*)d_in[9];  const float* b2 = (const float*)d_in[10];
    const float* l1W = (const float*)d_in[11]; const float* l1b = (const float*)d_in[12];
    const float* l3W = (const float*)d_in[13]; const float* l3b = (const float*)d_in[14];

    const int NPAD = 100352;  // 98 * 1024
    char* p = (char*)d_ws;
    float*          dinv      = (float*)p;          p += NPAD * 4;
    int*            cnt       = (int*)p;            p += NPAD * 4;
    int*            fill      = (int*)p;            p += NPAD * 4;
    int*            row_start = (int*)p;            p += NPAD * 4;
    int*            partial   = (int*)p;            p += 128 * 4;
    int2*           edges     = (int2*)p;           p += (size_t)N_EDGES * 8;
    unsigned short* xbA       = (unsigned short*)p; p += (size_t)N_TEAMS * 64 * 2;
    unsigned short* xbB       = (unsigned short*)p; p += (size_t)N_TEAMS * 64 * 2;
    float*          z2        = (float*)p;          p += (size_t)BATCH * 3 * 4;
    float*          stats     = (float*)p;

    const int scanBlocks = NPAD / 1024;  // 98

    // ---- CSR build (once, reused by all 3 layers) ----
    k_init<<<(N_TEAMS + 255) / 256, 256, 0, stream>>>(dinv, cnt, fill, N_TEAMS);
    k_hist<<<(N_EDGES + 255) / 256, 256, 0, stream>>>(dst, ew, dinv, cnt, N_EDGES);
    k_dinv<<<(N_TEAMS + 255) / 256, 256, 0, stream>>>(dinv, N_TEAMS);
    k_scan1<<<scanBlocks, 1024, 0, stream>>>(cnt, row_start, partial, N_TEAMS);
    k_scan2<<<1, 128, 0, stream>>>(partial, scanBlocks);
    k_scan3<<<scanBlocks, 1024, 0, stream>>>(row_start, partial);
    k_bucket<<<(N_EDGES + 255) / 256, 256, 0, stream>>>(src, dst, ew, dinv, row_start,
                                                        fill, edges, N_EDGES);
    k_cvt<<<(N_TEAMS * 64 / 4 + 255) / 256, 256, 0, stream>>>(emb, xbA, N_TEAMS * 64 / 4);

    const int layer_grid = N_TEAMS * 64 / 256;  // 25000, exact

    // layer 0..2 fused: agg + GEMM + bias + leaky
    k_layer<<<layer_grid, 256, 0, stream>>>(xbA, row_start, cnt, edges, dinv, W0, b0, xbB, N_TEAMS);
    k_layer<<<layer_grid, 256, 0, stream>>>(xbB, row_start, cnt, edges, dinv, W1, b1, xbA, N_TEAMS);
    k_layer<<<layer_grid, 256, 0, stream>>>(xbA, row_start, cnt, edges, dinv, W2, b2, xbB, N_TEAMS);

    // head + column log-softmax
    k_head<<<(BATCH + 255) / 256, 256, 0, stream>>>(xbB, home, away, l1W, l1b, l3W, l3b, z2, BATCH);
    k_stats<<<1, 1024, 0, stream>>>(z2, stats, BATCH);
    k_final<<<(BATCH * 3 + 255) / 256, 256, 0, stream>>>(z2, stats, (float*)d_out, BATCH * 3);
}